// Round 4
// baseline (2352.554 us; speedup 1.0000x reference)
//
#include <hip/hip_runtime.h>
#include <hip/hip_bf16.h>
#include <math.h>

namespace {
constexpr int NL  = 2;          // layers
constexpr int H   = 2048;
constexpr int NH  = 16;
constexpr int NKV = 2;
constexpr int HD  = 128;
constexpr int FF  = 11008;
constexpr int BB  = 32;         // batch
constexpr int SS  = 64;         // seq
constexpr int RR  = 16;         // lora rank
constexpr int TT  = BB * SS;    // 2048 tokens
constexpr int KVD = NKV * HD;   // 256
constexpr int QKVD = H + 2 * KVD; // 2560 fused qkv width
constexpr int PH  = 1024, TDm = 512;
constexpr float LSCALE = 2.0f;  // lora alpha/r
}

typedef __bf16 bf16x8 __attribute__((ext_vector_type(8)));
typedef float  f32x4  __attribute__((ext_vector_type(4)));

__device__ __forceinline__ ushort4 f4_to_bf4(float4 r) {
  __hip_bfloat16 a = __float2bfloat16(r.x), b = __float2bfloat16(r.y),
                 c = __float2bfloat16(r.z), d = __float2bfloat16(r.w);
  return make_ushort4(*(unsigned short*)&a, *(unsigned short*)&b,
                      *(unsigned short*)&c, *(unsigned short*)&d);
}

// counted vmcnt wait (literal immediates only)
template <int N> __device__ __forceinline__ void wait_vm() {
  static_assert(N == 0 || N == 3 || N == 4 || N == 6 || N == 8 || N == 12, "add case");
  if constexpr (N == 0)      asm volatile("s_waitcnt vmcnt(0)" ::: "memory");
  else if constexpr (N == 3) asm volatile("s_waitcnt vmcnt(3)" ::: "memory");
  else if constexpr (N == 4) asm volatile("s_waitcnt vmcnt(4)" ::: "memory");
  else if constexpr (N == 6) asm volatile("s_waitcnt vmcnt(6)" ::: "memory");
  else if constexpr (N == 8) asm volatile("s_waitcnt vmcnt(8)" ::: "memory");
  else                       asm volatile("s_waitcnt vmcnt(12)" ::: "memory");
}

// ---------------- embedding gather ----------------
__global__ __launch_bounds__(256) void k_embed(const int* __restrict__ ids,
                                               const float* __restrict__ emb,
                                               float* __restrict__ h) {
  int t = blockIdx.x;
  long id = ids[t];
  const float4* src = reinterpret_cast<const float4*>(emb + id * (long)H);
  float4* dst = reinterpret_cast<float4*>(h + (long)t * H);
  for (int i = threadIdx.x; i < H / 4; i += 256) dst[i] = src[i];
}

// ---------------- fp32 -> bf16 convert ----------------
__global__ __launch_bounds__(256) void k_cvt(const float* __restrict__ src,
                                             __hip_bfloat16* __restrict__ dst, long n) {
  long i = ((long)blockIdx.x * 256 + threadIdx.x) * 4;
  if (i >= n) return;
  float4 v = *reinterpret_cast<const float4*>(src + i);
  *reinterpret_cast<ushort4*>(dst + i) = f4_to_bf4(v);
}

// ---------------- rmsnorm (block per token), dual fp32+bf16 out -----------
__global__ __launch_bounds__(256) void k_rmsnorm(const float* __restrict__ in,
                                                 const float* __restrict__ w,
                                                 float* __restrict__ out,
                                                 __hip_bfloat16* __restrict__ outb) {
  int t = blockIdx.x, tid = threadIdx.x;
  const float4* xr = reinterpret_cast<const float4*>(in + (long)t * H);
  float4 v0 = xr[tid], v1 = xr[tid + 256];
  float ss = v0.x*v0.x + v0.y*v0.y + v0.z*v0.z + v0.w*v0.w
           + v1.x*v1.x + v1.y*v1.y + v1.z*v1.z + v1.w*v1.w;
  #pragma unroll
  for (int off = 32; off; off >>= 1) ss += __shfl_xor(ss, off);
  __shared__ float sred[4];
  if ((tid & 63) == 0) sred[tid >> 6] = ss;
  __syncthreads();
  float scale = rsqrtf((sred[0] + sred[1] + sred[2] + sred[3]) * (1.0f / H) + 1e-6f);
  const float4* wr = reinterpret_cast<const float4*>(w);
  float4 w0 = wr[tid], w1 = wr[tid + 256];
  float4 r0 = make_float4(v0.x*scale*w0.x, v0.y*scale*w0.y, v0.z*scale*w0.z, v0.w*scale*w0.w);
  float4 r1 = make_float4(v1.x*scale*w1.x, v1.y*scale*w1.y, v1.z*scale*w1.z, v1.w*scale*w1.w);
  float4* o = reinterpret_cast<float4*>(out + (long)t * H);
  o[tid] = r0; o[tid + 256] = r1;
  ushort4* ob = reinterpret_cast<ushort4*>(outb + (long)t * H);
  ob[tid] = f4_to_bf4(r0); ob[tid + 256] = f4_to_bf4(r1);
}

// ===================== MFMA bf16 GEMM (3-buf counted-vmcnt, swizzled) ======
// C = A[M,K] @ W[N,K]^T (+epilogue). LDS chunk swizzle: LDS chunk (r,c)
// holds global chunk (r, c ^ ((r>>1)&3)); source pre-swizzled (rule 21),
// fragment reads use the same XOR -> conflict-free (verified: r3 conflicts=0).
enum { ME_BIAS_F32 = 0, ME_ACC_F32 = 1, ME_SILU_BF16 = 2, ME_MUL_BF16 = 3 };

__device__ __forceinline__ int raster_sw(int bid, int nwg) {
  // bijective XCD remap (m204): XCD (bid&7) gets a contiguous sw-chunk
  int q8 = nwg >> 3, r8 = nwg & 7;
  int xcd = bid & 7, pos = bid >> 3;
  return (xcd < r8 ? xcd * (q8 + 1) : r8 * (q8 + 1) + (xcd - r8) * q8) + pos;
}

template <int EPI, int BM, int BN, int WROWS, int WCOLS>
__global__ __launch_bounds__(256) void k_mgemm(
    const __hip_bfloat16* __restrict__ Abf,
    const __hip_bfloat16* __restrict__ Wbf,
    const float* __restrict__ bias,
    float* __restrict__ Cf,
    __hip_bfloat16* Cb,                    // no restrict: may alias gate
    const __hip_bfloat16* gate,
    int M, int N, int K) {
  constexpr int BK = 32;
  constexpr int WTM = BM / WROWS, WTN = BN / WCOLS;
  constexpr int FM = WTM / 16, FN = WTN / 16;
  constexpr int ACH = BM * BK / 8, BCH = BN * BK / 8;  // 16B chunks per tile
  constexpr int LPT = (ACH + BCH) / 256;               // loads per thread/stage
  __shared__ __align__(16) __bf16 As[3][BM * BK];
  __shared__ __align__(16) __bf16 Bs[3][BN * BK];
  const int tid = threadIdx.x;
  const int sw = raster_sw(blockIdx.x, gridDim.x);
  const int ntm = M / BM;
  const int bm = (sw % ntm) * BM, bn = (sw / ntm) * BN;   // col-major raster
  const int lane = tid & 63, wv = tid >> 6;
  const int wm = (wv / WCOLS) * WTM, wn = (wv % WCOLS) * WTN;
  const int lr15 = lane & 15;
  const int lks = (((lane >> 4) << 3)) ^ ((((lr15 >> 1) & 3)) << 3);
  f32x4 acc[FM][FN] = {};
  const __bf16* Ag = reinterpret_cast<const __bf16*>(Abf) + (long)bm * K;
  const __bf16* Bg = reinterpret_cast<const __bf16*>(Wbf) + (long)bn * K;

  auto stage = [&](int buf, int k0) {
    #pragma unroll
    for (int i = tid; i < ACH; i += 256)
      __builtin_amdgcn_global_load_lds(
          (const __attribute__((address_space(1))) void*)
            (Ag + (long)(i >> 2) * K + k0 + (((i & 3) ^ ((i >> 3) & 3)) << 3)),
          (__attribute__((address_space(3))) void*)(&As[buf][i * 8]), 16, 0, 0);
    #pragma unroll
    for (int i = tid; i < BCH; i += 256)
      __builtin_amdgcn_global_load_lds(
          (const __attribute__((address_space(1))) void*)
            (Bg + (long)(i >> 2) * K + k0 + (((i & 3) ^ ((i >> 3) & 3)) << 3)),
          (__attribute__((address_space(3))) void*)(&Bs[buf][i * 8]), 16, 0, 0);
  };
  auto compute = [&](int buf) {
    bf16x8 af[FM], bfr[FN];
    #pragma unroll
    for (int m = 0; m < FM; ++m)
      af[m] = *reinterpret_cast<const bf16x8*>(&As[buf][(wm + m * 16 + lr15) * BK + lks]);
    #pragma unroll
    for (int n = 0; n < FN; ++n)
      bfr[n] = *reinterpret_cast<const bf16x8*>(&Bs[buf][(wn + n * 16 + lr15) * BK + lks]);
    #pragma unroll
    for (int m = 0; m < FM; ++m)
      #pragma unroll
      for (int n = 0; n < FN; ++n)
        acc[m][n] = __builtin_amdgcn_mfma_f32_16x16x32_bf16(af[m], bfr[n], acc[m][n], 0, 0, 0);
  };

  const int NS = K / BK;
  stage(0, 0);
  stage(1, BK);
  wait_vm<LPT>();                         // buf0 landed; buf1 may be in flight
  __builtin_amdgcn_s_barrier();
  for (int t = 0; t < NS; ++t) {
    if (t + 2 < NS) stage((t + 2) % 3, (t + 2) * BK);
    compute(t % 3);
    if (t + 1 < NS) {
      if (t + 2 < NS) wait_vm<LPT>();     // (t+1)'s loads done; (t+2)'s in flight
      else            wait_vm<0>();
      __builtin_amdgcn_s_barrier();
    }
  }

  const int r0 = (lane >> 4) << 2;
  #pragma unroll
  for (int m = 0; m < FM; ++m)
    #pragma unroll
    for (int n = 0; n < FN; ++n) {
      const int col = bn + wn + n * 16 + lr15;
      const long rowb = bm + wm + m * 16 + r0;
      #pragma unroll
      for (int j = 0; j < 4; ++j) {
        const long off = (rowb + j) * N + col;
        float v = acc[m][n][j];
        if constexpr (EPI == ME_BIAS_F32) {
          Cf[off] = v + bias[col];
        } else if constexpr (EPI == ME_ACC_F32) {
          Cf[off] += v;
        } else if constexpr (EPI == ME_SILU_BF16) {
          Cb[off] = __float2bfloat16(v / (1.0f + expf(-v)));
        } else {
          float g = __bfloat162float(gate[off]);
          Cb[off] = __float2bfloat16(v * g);
        }
      }
    }
}

// ------------- fused SwiGLU: out = silu(A@Wg^T) * (A@Wu^T), bf16 ----------
template <int BM, int BN, int WROWS, int WCOLS>
__global__ __launch_bounds__(256, 2) void k_swiglu(
    const __hip_bfloat16* __restrict__ Abf,
    const __hip_bfloat16* __restrict__ Wgb,
    const __hip_bfloat16* __restrict__ Wub,
    __hip_bfloat16* __restrict__ Cb,
    int M, int N, int K) {
  constexpr int BK = 32;
  constexpr int WTM = BM / WROWS, WTN = BN / WCOLS;
  constexpr int FM = WTM / 16, FN = WTN / 16;
  constexpr int ACH = BM * BK / 8, BCH = BN * BK / 8;
  constexpr int LPT = (ACH + 2 * BCH) / 256;
  __shared__ __align__(16) __bf16 As[3][BM * BK];
  __shared__ __align__(16) __bf16 Gs[3][BN * BK];
  __shared__ __align__(16) __bf16 Us[3][BN * BK];
  const int tid = threadIdx.x;
  const int sw = raster_sw(blockIdx.x, gridDim.x);
  const int ntm = M / BM;
  const int bm = (sw % ntm) * BM, bn = (sw / ntm) * BN;
  const int lane = tid & 63, wv = tid >> 6;
  const int wm = (wv / WCOLS) * WTM, wn = (wv % WCOLS) * WTN;
  const int lr15 = lane & 15;
  const int lks = (((lane >> 4) << 3)) ^ ((((lr15 >> 1) & 3)) << 3);
  f32x4 accg[FM][FN] = {}, accu[FM][FN] = {};
  const __bf16* Ag = reinterpret_cast<const __bf16*>(Abf) + (long)bm * K;
  const __bf16* Gg = reinterpret_cast<const __bf16*>(Wgb) + (long)bn * K;
  const __bf16* Ug = reinterpret_cast<const __bf16*>(Wub) + (long)bn * K;

  auto stage = [&](int buf, int k0) {
    #pragma unroll
    for (int i = tid; i < ACH; i += 256)
      __builtin_amdgcn_global_load_lds(
          (const __attribute__((address_space(1))) void*)
            (Ag + (long)(i >> 2) * K + k0 + (((i & 3) ^ ((i >> 3) & 3)) << 3)),
          (__attribute__((address_space(3))) void*)(&As[buf][i * 8]), 16, 0, 0);
    #pragma unroll
    for (int i = tid; i < BCH; i += 256)
      __builtin_amdgcn_global_load_lds(
          (const __attribute__((address_space(1))) void*)
            (Gg + (long)(i >> 2) * K + k0 + (((i & 3) ^ ((i >> 3) & 3)) << 3)),
          (__attribute__((address_space(3))) void*)(&Gs[buf][i * 8]), 16, 0, 0);
    #pragma unroll
    for (int i = tid; i < BCH; i += 256)
      __builtin_amdgcn_global_load_lds(
          (const __attribute__((address_space(1))) void*)
            (Ug + (long)(i >> 2) * K + k0 + (((i & 3) ^ ((i >> 3) & 3)) << 3)),
          (__attribute__((address_space(3))) void*)(&Us[buf][i * 8]), 16, 0, 0);
  };
  auto compute = [&](int buf) {
    bf16x8 af[FM], gf[FN], uf[FN];
    #pragma unroll
    for (int m = 0; m < FM; ++m)
      af[m] = *reinterpret_cast<const bf16x8*>(&As[buf][(wm + m * 16 + lr15) * BK + lks]);
    #pragma unroll
    for (int n = 0; n < FN; ++n) {
      gf[n] = *reinterpret_cast<const bf16x8*>(&Gs[buf][(wn + n * 16 + lr15) * BK + lks]);
      uf[n] = *reinterpret_cast<const bf16x8*>(&Us[buf][(wn + n * 16 + lr15) * BK + lks]);
    }
    #pragma unroll
    for (int m = 0; m < FM; ++m)
      #pragma unroll
      for (int n = 0; n < FN; ++n) {
        accg[m][n] = __builtin_amdgcn_mfma_f32_16x16x32_bf16(af[m], gf[n], accg[m][n], 0, 0, 0);
        accu[m][n] = __builtin_amdgcn_mfma_f32_16x16x32_bf16(af[m], uf[n], accu[m][n], 0, 0, 0);
      }
  };

  const int NS = K / BK;
  stage(0, 0);
  stage(1, BK);
  wait_vm<LPT>();
  __builtin_amdgcn_s_barrier();
  for (int t = 0; t < NS; ++t) {
    if (t + 2 < NS) stage((t + 2) % 3, (t + 2) * BK);
    compute(t % 3);
    if (t + 1 < NS) {
      if (t + 2 < NS) wait_vm<LPT>();
      else            wait_vm<0>();
      __builtin_amdgcn_s_barrier();
    }
  }

  const int r0 = (lane >> 4) << 2;
  #pragma unroll
  for (int m = 0; m < FM; ++m)
    #pragma unroll
    for (int n = 0; n < FN; ++n) {
      const int col = bn + wn + n * 16 + lr15;
      const long rowb = bm + wm + m * 16 + r0;
      #pragma unroll
      for (int j = 0; j < 4; ++j) {
        float g = accg[m][n][j], u = accu[m][n][j];
        Cb[(rowb + j) * N + col] = __float2bfloat16((g / (1.0f + expf(-g))) * u);
      }
    }
}

// ---------------- fp32 GEMM (head only, tiny M) ----------------
enum { EPI_STORE = 0, EPI_GELU = 3 };

template <int EPI, bool HAS_BIAS>
__global__ __launch_bounds__(256) void k_gemm(const float* __restrict__ A,
                                              const float* __restrict__ W,
                                              const float* __restrict__ bias,
                                              float* __restrict__ C,
                                              int M, int N, int K) {
  constexpr int BM = 64, BN = 64, BK = 16;
  __shared__ float As[BK][BM + 4];
  __shared__ float Ws[BK][BN + 4];
  const int bm = blockIdx.y * BM, bn = blockIdx.x * BN;
  const int tid = threadIdx.x;
  const int lr = tid >> 2;
  const int lc = (tid & 3) << 2;
  const int ty = tid >> 4, tx = tid & 15;
  float acc[4][4] = {};
  const int arow = bm + lr;
  const bool aok = arow < M;
  const float* Ap = A + (long)arow * K + lc;
  const float* Wp = W + (long)(bn + lr) * K + lc;
  for (int k0 = 0; k0 < K; k0 += BK) {
    float4 av = aok ? *reinterpret_cast<const float4*>(Ap + k0) : make_float4(0.f, 0.f, 0.f, 0.f);
    float4 wv = *reinterpret_cast<const float4*>(Wp + k0);
    As[lc + 0][lr] = av.x; As[lc + 1][lr] = av.y; As[lc + 2][lr] = av.z; As[lc + 3][lr] = av.w;
    Ws[lc + 0][lr] = wv.x; Ws[lc + 1][lr] = wv.y; Ws[lc + 2][lr] = wv.z; Ws[lc + 3][lr] = wv.w;
    __syncthreads();
    #pragma unroll
    for (int k = 0; k < BK; ++k) {
      float4 a4 = *reinterpret_cast<const float4*>(&As[k][ty << 2]);
      float4 b4 = *reinterpret_cast<const float4*>(&Ws[k][tx << 2]);
      float a[4] = {a4.x, a4.y, a4.z, a4.w};
      float b[4] = {b4.x, b4.y, b4.z, b4.w};
      #pragma unroll
      for (int i = 0; i < 4; ++i)
        #pragma unroll
        for (int j = 0; j < 4; ++j) acc[i][j] = fmaf(a[i], b[j], acc[i][j]);
    }
    __syncthreads();
  }
  const int col = bn + (tx << 2);
  #pragma unroll
  for (int i = 0; i < 4; ++i) {
    int row = bm + (ty << 2) + i;
    if (row < M) {
      float4 r = make_float4(acc[i][0], acc[i][1], acc[i][2], acc[i][3]);
      if (HAS_BIAS) {
        float4 bv = *reinterpret_cast<const float4*>(bias + col);
        r.x += bv.x; r.y += bv.y; r.z += bv.z; r.w += bv.w;
      }
      if (EPI == EPI_GELU) {
        r.x = 0.5f * r.x * (1.0f + erff(r.x * 0.70710678118654752f));
        r.y = 0.5f * r.y * (1.0f + erff(r.y * 0.70710678118654752f));
        r.z = 0.5f * r.z * (1.0f + erff(r.z * 0.70710678118654752f));
        r.w = 0.5f * r.w * (1.0f + erff(r.w * 0.70710678118654752f));
      }
      *reinterpret_cast<float4*>(C + (long)row * N + col) = r;
    }
  }
}

// ---------------- lora down: tmp[T,16] = x[T,H] @ A[16,H]^T ----------------
__global__ __launch_bounds__(256) void k_lora_down(const float* __restrict__ x,
                                                   const float* __restrict__ A,
                                                   float* __restrict__ tmp) {
  int t = blockIdx.x, tid = threadIdx.x;
  int r = tid & 15, sl = tid >> 4;
  const float* xr = x + (long)t * H + sl * 128;
  const float* Ar = A + (long)r * H + sl * 128;
  float p = 0.f;
  #pragma unroll 8
  for (int kk = 0; kk < 128; kk += 4) {
    float4 xv = *reinterpret_cast<const float4*>(xr + kk);
    float4 av = *reinterpret_cast<const float4*>(Ar + kk);
    p = fmaf(xv.x, av.x, p); p = fmaf(xv.y, av.y, p);
    p = fmaf(xv.z, av.z, p); p = fmaf(xv.w, av.w, p);
  }
  __shared__ float red[16][17];
  red[sl][r] = p;
  __syncthreads();
  if (tid < 16) {
    float s = 0.f;
    #pragma unroll
    for (int i = 0; i < 16; ++i) s += red[i][tid];
    tmp[t * RR + tid] = s;
  }
}

// ------ lora up add (strided C): C[t*ldC + n] += 2 * tmp[t,:] @ Bm[n,:] ----
__global__ __launch_bounds__(256) void k_lora_add(const float* __restrict__ tmp,
                                                  const float* __restrict__ Bm,
                                                  float* __restrict__ C, int ldC, int N) {
  long idx = (long)blockIdx.x * 256 + threadIdx.x;
  if (idx >= (long)TT * N) return;
  int t = (int)(idx / N), n = (int)(idx % N);
  const float* tr = tmp + (long)t * RR;
  const float* br = Bm + (long)n * RR;
  float s = 0.f;
  #pragma unroll
  for (int r = 0; r < RR; ++r) s = fmaf(tr[r], br[r], s);
  C[(long)t * ldC + n] += LSCALE * s;
}

// ---------------- RoPE in place on fused qkv [T, QKVD] ---------------------
__global__ __launch_bounds__(256) void k_rope(float* __restrict__ qkv) {
  int t = blockIdx.x;
  float pos = (float)(t & (SS - 1));
  float* row = qkv + (long)t * QKVD;
  for (int idx = threadIdx.x; idx < NH * 64 + NKV * 64; idx += 256) {
    float* base;
    int j;
    if (idx < NH * 64) {
      int head = idx >> 6; j = idx & 63;
      base = row + head * HD;
    } else {
      int i2 = idx - NH * 64;
      int head = i2 >> 6; j = i2 & 63;
      base = row + H + head * HD;
    }
    float inv = 1.0f / powf(1.0e6f, (float)(2 * j) * (1.0f / HD));
    float ang = pos * inv;
    float cs = cosf(ang), sn = sinf(ang);
    float lo = base[j], hi = base[j + 64];
    base[j]      = lo * cs - hi * sn;
    base[j + 64] = hi * cs + lo * sn;
  }
}

// ---------------- fused attention: one wave per (b, head, query) -----------
__global__ __launch_bounds__(64) void k_attn(const float* __restrict__ qkv,
                                             const int* __restrict__ mask,
                                             float* __restrict__ o,
                                             __hip_bfloat16* __restrict__ obf) {
  int flat = blockIdx.x;
  int qi = flat & (SS - 1);
  int hh = (flat >> 6) & (NH - 1);
  int b  = flat >> 10;
  int lane = threadIdx.x;
  int kv = hh >> 3;  // NH/NKV = 8
  long t = (long)b * SS + qi;
  const float* qr = qkv + t * QKVD + hh * HD;
  const float* kr = qkv + ((long)b * SS + lane) * QKVD + H + kv * HD;
  float dot = 0.f;
  #pragma unroll 8
  for (int d = 0; d < HD; d += 4) {
    float4 qv = *reinterpret_cast<const float4*>(qr + d);
    float4 kvv = *reinterpret_cast<const float4*>(kr + d);
    dot = fmaf(qv.x, kvv.x, dot); dot = fmaf(qv.y, kvv.y, dot);
    dot = fmaf(qv.z, kvv.z, dot); dot = fmaf(qv.w, kvv.w, dot);
  }
  bool keep = (lane <= qi) && (mask[b * SS + lane] > 0);
  float sc = dot * 0.08838834764831845f + (keep ? 0.f : -1e9f);
  float m = sc;
  #pragma unroll
  for (int off = 32; off; off >>= 1) m = fmaxf(m, __shfl_xor(m, off));
  float e = expf(sc - m);
  float s = e;
  #pragma unroll
  for (int off = 32; off; off >>= 1) s += __shfl_xor(s, off);
  float p = e / s;
  __shared__ float pl[64];
  pl[lane] = p;
  __syncthreads();
  float o0 = 0.f, o1 = 0.f;
  const float* vb = qkv + (long)b * SS * QKVD + H + KVD + kv * HD;
  for (int ki = 0; ki < SS; ++ki) {
    float pp = pl[ki];
    o0 = fmaf(pp, vb[(long)ki * QKVD + lane], o0);
    o1 = fmaf(pp, vb[(long)ki * QKVD + lane + 64], o1);
  }
  long oidx = t * H + hh * HD + lane;
  o[oidx] = o0;
  o[oidx + 64] = o1;
  __hip_bfloat16 b0 = __float2bfloat16(o0), b1 = __float2bfloat16(o1);
  obf[oidx] = b0;
  obf[oidx + 64] = b1;
}

// ---------------- pool last valid token ----------------
__global__ __launch_bounds__(256) void k_pool(const float* __restrict__ x,
                                              const int* __restrict__ mask,
                                              float* __restrict__ pooled) {
  int b = blockIdx.x;
  __shared__ int len;
  if (threadIdx.x == 0) {
    int L2 = 0;
    for (int i = 0; i < SS; ++i) L2 += (mask[b * SS + i] > 0);
    len = L2;
  }
  __syncthreads();
  const float4* sp = reinterpret_cast<const float4*>(x + ((long)b * SS + len - 1) * H);
  float4* dp = reinterpret_cast<float4*>(pooled + (long)b * H);
  for (int i = threadIdx.x; i < H / 4; i += 256) dp[i] = sp[i];
}

// ---------------- launch helpers ----------------
static inline int cvt_grid(long n) { return (int)((n / 4 + 255) / 256); }

extern "C" void kernel_launch(void* const* d_in, const int* in_sizes, int n_in,
                              void* d_out, int out_size, void* d_ws, size_t ws_size,
                              hipStream_t stream) {
  const int*   ids    = (const int*)d_in[0];
  const int*   mask   = (const int*)d_in[1];
  const float* embed  = (const float*)d_in[2];
  const float* Wq     = (const float*)d_in[3];
  const float* bq     = (const float*)d_in[4];
  const float* Aq     = (const float*)d_in[5];
  const float* Bq     = (const float*)d_in[6];
  const float* Wk     = (const float*)d_in[7];
  const float* bk     = (const float*)d_in[8];
  const float* Ak     = (const float*)d_in[9];
  const float* Bk     = (const float*)d_in[10];
  const float* Wv     = (const float*)d_in[11];
  const float* bv     = (const float*)d_in[12];
  const float* Av     = (const float*)d_in[13];
  const float* Bv     = (const float*)d_in[14];
  const float* Wo     = (const float*)d_in[15];
  const float* Ao     = (const float*)d_in[16];
  const float* Bo     = (const float*)d_in[17];
  const float* ln1    = (const float*)d_in[18];
  const float* ln2    = (const float*)d_in[19];
  const float* Wg     = (const float*)d_in[20];
  const float* Wu     = (const float*)d_in[21];
  const float* Wd     = (const float*)d_in[22];
  const float* norm_f = (const float*)d_in[23];
  const float* W1     = (const float*)d_in[24];
  const float* b1     = (const float*)d_in[25];
  const float* W2     = (const float*)d_in[26];
  const float* b2     = (const float*)d_in[27];

  // ---- workspace layout ----
  float* ws = (float*)d_ws;
  float* h       = ws;                          // [T,H] fp32 residual
  float* x       = h    + (long)TT * H;         // [T,H] fp32 (normed / attn out)
  float* qkv     = x    + (long)TT * H;         // [T,QKVD] fp32
  float* tmpR    = qkv  + (long)TT * QKVD;      // [T,R]
  float* pooled  = tmpR + (long)TT * RR;        // [B,H]
  float* zz      = pooled + (long)BB * H;       // [B,PH]
  float* biascat = zz   + (long)BB * PH;        // [QKVD]
  float* endf32  = biascat + QKVD;
  __hip_bfloat16* x_bf = (__hip_bfloat16*)endf32;             // [T,H] bf16
  __hip_bfloat16* ffbf = x_bf + (long)TT * H;                 // [T,FF] bf16
  __hip_bfloat16* wbf  = ffbf + (long)TT * FF;                // [FF,H] bf16 weight scratch
  __hip_bfloat16* wbf2 = wbf  + (long)FF * H;                 // [FF,H] second weight scratch
  size_t need_fused = (size_t)((char*)(wbf2 + (long)FF * H) - (char*)d_ws);
  bool fused_ok = ws_size >= need_fused;

  k_embed<<<TT, 256, 0, stream>>>(ids, embed, h);

  for (int l = 0; l < NL; ++l) {
    const long lHH = (long)l * H * H;
    const long lKH = (long)l * KVD * H;
    const long lRH = (long)l * RR * H;
    // x,x_bf = rms(h, ln1)
    k_rmsnorm<<<TT, 256, 0, stream>>>(h, ln1 + l * H, x, x_bf);
    // fused QKV weight + bias
    k_cvt<<<cvt_grid((long)H * H), 256, 0, stream>>>(Wq + lHH, wbf, (long)H * H);
    k_cvt<<<cvt_grid((long)KVD * H), 256, 0, stream>>>(Wk + lKH, wbf + (long)H * H, (long)KVD * H);
    k_cvt<<<cvt_grid((long)KVD * H), 256, 0, stream>>>(Wv + lKH, wbf + (long)(H + KVD) * H, (long)KVD * H);
    hipMemcpyAsync(biascat,           bq + (long)l * H,   H * sizeof(float),   hipMemcpyDeviceToDevice, stream);
    hipMemcpyAsync(biascat + H,       bk + (long)l * KVD, KVD * sizeof(float), hipMemcpyDeviceToDevice, stream);
    hipMemcpyAsync(biascat + H + KVD, bv + (long)l * KVD, KVD * sizeof(float), hipMemcpyDeviceToDevice, stream);
    // qkv = x @ [Wq;Wk;Wv]^T + bias
    k_mgemm<ME_BIAS_F32, 128, 128, 2, 2><<<(TT / 128) * (QKVD / 128), 256, 0, stream>>>(
        x_bf, wbf, biascat, qkv, nullptr, nullptr, TT, QKVD, H);
    // lora adds for q/k/v
    k_lora_down<<<TT, 256, 0, stream>>>(x, Aq + lRH, tmpR);
    k_lora_add<<<((long)TT * H + 255) / 256, 256, 0, stream>>>(tmpR, Bq + (long)l * H * RR, qkv, QKVD, H);
    k_lora_down<<<TT, 256, 0, stream>>>(x, Ak + lRH, tmpR);
    k_lora_add<<<((long)TT * KVD + 255) / 256, 256, 0, stream>>>(tmpR, Bk + (long)l * KVD * RR, qkv + H, QKVD, KVD);
    k_lora_down<<<TT, 256, 0, stream>>>(x, Av + lRH, tmpR);
    k_lora_add<<<((long)TT * KVD + 255) / 256, 256, 0, stream>>>(tmpR, Bv + (long)l * KVD * RR, qkv + H + KVD, QKVD, KVD);
    // rope + attention (writes fp32 x and bf16 x_bf)
    k_rope<<<TT, 256, 0, stream>>>(qkv);
    k_attn<<<BB * NH * SS, 64, 0, stream>>>(qkv, mask, x, x_bf);
    // h += attn @ Wo^T + lora
    k_lora_down<<<TT, 256, 0, stream>>>(x, Ao + lRH, tmpR);
    k_cvt<<<cvt_grid((long)H * H), 256, 0, stream>>>(Wo + lHH, wbf, (long)H * H);
    k_mgemm<ME_ACC_F32, 128, 128, 2, 2><<<(TT / 128) * (H / 128), 256, 0, stream>>>(
        x_bf, wbf, nullptr, h, nullptr, nullptr, TT, H, H);
    k_lora_add<<<((long)TT * H + 255) / 256, 256, 0, stream>>>(tmpR, Bo + (long)l * H * RR, h, H, H);
    // MLP
    k_rmsnorm<<<TT, 256, 0, stream>>>(h, ln2 + l * H, x, x_bf);
    if (fused_ok) {
      k_cvt<<<cvt_grid((long)FF * H), 256, 0, stream>>>(Wg + (long)l * FF * H, wbf, (long)FF * H);
      k_cvt<<<cvt_grid((long)FF * H), 256, 0, stream>>>(Wu + (long)l * FF * H, wbf2, (long)FF * H);
      k_swiglu<128, 128, 2, 2><<<(TT / 128) * (FF / 128), 256, 0, stream>>>(
          x_bf, wbf, wbf2, ffbf, TT, FF, H);
    } else {
      k_cvt<<<cvt_grid((long)FF * H), 256, 0, stream>>>(Wg + (long)l * FF * H, wbf, (long)FF * H);
      k_mgemm<ME_SILU_BF16, 128, 128, 2, 2><<<(TT / 128) * (FF / 128), 256, 0, stream>>>(
          x_bf, wbf, nullptr, nullptr, ffbf, nullptr, TT, FF, H);
      k_cvt<<<cvt_grid((long)FF * H), 256, 0, stream>>>(Wu + (long)l * FF * H, wbf, (long)FF * H);
      k_mgemm<ME_MUL_BF16, 128, 128, 2, 2><<<(TT / 128) * (FF / 128), 256, 0, stream>>>(
          x_bf, wbf, nullptr, nullptr, ffbf, ffbf, TT, FF, H);
    }
    k_cvt<<<cvt_grid((long)H * FF), 256, 0, stream>>>(Wd + (long)l * H * FF, wbf, (long)H * FF);
    k_mgemm<ME_ACC_F32, 128, 128, 2, 2><<<(TT / 128) * (H / 128), 256, 0, stream>>>(
        ffbf, wbf, nullptr, h, nullptr, nullptr, TT, H, FF);
  }

  // final norm, pool, head (fp32)
  k_rmsnorm<<<TT, 256, 0, stream>>>(h, norm_f, x, x_bf);
  k_pool<<<BB, 256, 0, stream>>>(x, mask, pooled);
  k_gemm<EPI_GELU, true><<<dim3(PH / 64, 1), 256, 0, stream>>>(pooled, W1, b1, zz, BB, PH, H);
  k_gemm<EPI_STORE, true><<<dim3(TDm / 64, 1), 256, 0, stream>>>(zz, W2, b2, (float*)d_out, BB, TDm, PH);
}

// Round 5
// 2117.159 us; speedup vs baseline: 1.1112x; 1.1112x over previous
//
#include <hip/hip_runtime.h>
#include <hip/hip_bf16.h>
#include <math.h>

namespace {
constexpr int NL  = 2;          // layers
constexpr int H   = 2048;
constexpr int NH  = 16;
constexpr int NKV = 2;
constexpr int HD  = 128;
constexpr int FF  = 11008;
constexpr int BB  = 32;         // batch
constexpr int SS  = 64;         // seq
constexpr int RR  = 16;         // lora rank
constexpr int TT  = BB * SS;    // 2048 tokens
constexpr int KVD = NKV * HD;   // 256
constexpr int QKVD = H + 2 * KVD; // 2560 fused qkv width
constexpr int PH  = 1024, TDm = 512;
constexpr float LSCALE = 2.0f;  // lora alpha/r
}

typedef __bf16 bf16x8 __attribute__((ext_vector_type(8)));
typedef float  f32x4  __attribute__((ext_vector_type(4)));

__device__ __forceinline__ ushort4 f4_to_bf4(float4 r) {
  __hip_bfloat16 a = __float2bfloat16(r.x), b = __float2bfloat16(r.y),
                 c = __float2bfloat16(r.z), d = __float2bfloat16(r.w);
  return make_ushort4(*(unsigned short*)&a, *(unsigned short*)&b,
                      *(unsigned short*)&c, *(unsigned short*)&d);
}

// ---------------- embedding gather ----------------
__global__ __launch_bounds__(256) void k_embed(const int* __restrict__ ids,
                                               const float* __restrict__ emb,
                                               float* __restrict__ h) {
  int t = blockIdx.x;
  long id = ids[t];
  const float4* src = reinterpret_cast<const float4*>(emb + id * (long)H);
  float4* dst = reinterpret_cast<float4*>(h + (long)t * H);
  for (int i = threadIdx.x; i < H / 4; i += 256) dst[i] = src[i];
}

// ---------------- fp32 -> bf16 convert ----------------
__global__ __launch_bounds__(256) void k_cvt(const float* __restrict__ src,
                                             __hip_bfloat16* __restrict__ dst, long n) {
  long i = ((long)blockIdx.x * 256 + threadIdx.x) * 4;
  if (i >= n) return;
  float4 v = *reinterpret_cast<const float4*>(src + i);
  *reinterpret_cast<ushort4*>(dst + i) = f4_to_bf4(v);
}

// ---------------- rmsnorm (block per token), dual fp32+bf16 out -----------
__global__ __launch_bounds__(256) void k_rmsnorm(const float* __restrict__ in,
                                                 const float* __restrict__ w,
                                                 float* __restrict__ out,
                                                 __hip_bfloat16* __restrict__ outb) {
  int t = blockIdx.x, tid = threadIdx.x;
  const float4* xr = reinterpret_cast<const float4*>(in + (long)t * H);
  float4 v0 = xr[tid], v1 = xr[tid + 256];
  float ss = v0.x*v0.x + v0.y*v0.y + v0.z*v0.z + v0.w*v0.w
           + v1.x*v1.x + v1.y*v1.y + v1.z*v1.z + v1.w*v1.w;
  #pragma unroll
  for (int off = 32; off; off >>= 1) ss += __shfl_xor(ss, off);
  __shared__ float sred[4];
  if ((tid & 63) == 0) sred[tid >> 6] = ss;
  __syncthreads();
  float scale = rsqrtf((sred[0] + sred[1] + sred[2] + sred[3]) * (1.0f / H) + 1e-6f);
  const float4* wr = reinterpret_cast<const float4*>(w);
  float4 w0 = wr[tid], w1 = wr[tid + 256];
  float4 r0 = make_float4(v0.x*scale*w0.x, v0.y*scale*w0.y, v0.z*scale*w0.z, v0.w*scale*w0.w);
  float4 r1 = make_float4(v1.x*scale*w1.x, v1.y*scale*w1.y, v1.z*scale*w1.z, v1.w*scale*w1.w);
  float4* o = reinterpret_cast<float4*>(out + (long)t * H);
  o[tid] = r0; o[tid + 256] = r1;
  ushort4* ob = reinterpret_cast<ushort4*>(outb + (long)t * H);
  ob[tid] = f4_to_bf4(r0); ob[tid + 256] = f4_to_bf4(r1);
}

// ===================== MFMA bf16 GEMM (512-thr 8-wave, 2-buf, swizzled) ====
// C = A[M,K] @ W[N,K]^T (+epilogue). 128x128 tile, 8 waves (2x4), per-wave
// 64x32 output. LDS chunk swizzle as r3 (verified conflicts=0). 2 waves/SIMD
// at grid ~= 1 block/CU: this is the TLP fix for the N=2048 GEMMs.
enum { ME_BIAS_F32 = 0, ME_ACC_F32 = 1, ME_SILU_BF16 = 2, ME_MUL_BF16 = 3 };

__device__ __forceinline__ int raster_sw(int bid, int nwg) {
  // bijective XCD remap (m204)
  int q8 = nwg >> 3, r8 = nwg & 7;
  int xcd = bid & 7, pos = bid >> 3;
  return (xcd < r8 ? xcd * (q8 + 1) : r8 * (q8 + 1) + (xcd - r8) * q8) + pos;
}

template <int EPI>
__global__ __launch_bounds__(512) void k_mgemm(
    const __hip_bfloat16* __restrict__ Abf,
    const __hip_bfloat16* __restrict__ Wbf,
    const float* __restrict__ bias,
    float* __restrict__ Cf,
    __hip_bfloat16* Cb,                    // no restrict: may alias gate
    const __hip_bfloat16* gate,
    int M, int N, int K) {
  constexpr int BM = 128, BN = 128, BK = 32;
  constexpr int FM = 4, FN = 2;            // per-wave 64x32
  constexpr int ACH = BM * BK / 8, BCH = BN * BK / 8;  // 512 chunks each
  __shared__ __align__(16) __bf16 As[2][BM * BK];
  __shared__ __align__(16) __bf16 Bs[2][BN * BK];
  const int tid = threadIdx.x;
  const int sw = raster_sw(blockIdx.x, gridDim.x);
  const int ntm = M / BM;
  const int bm = (sw % ntm) * BM, bn = (sw / ntm) * BN;   // col-major raster
  const int lane = tid & 63, wv = tid >> 6;               // 0..7
  const int wm = (wv >> 2) * 64, wn = (wv & 3) * 32;
  const int lr15 = lane & 15;
  const int lks = (((lane >> 4) << 3)) ^ ((((lr15 >> 1) & 3)) << 3);
  f32x4 acc[FM][FN] = {};
  const __bf16* Ag = reinterpret_cast<const __bf16*>(Abf) + (long)bm * K;
  const __bf16* Bg = reinterpret_cast<const __bf16*>(Wbf) + (long)bn * K;

  auto stage = [&](int buf, int k0) {
    #pragma unroll
    for (int i = tid; i < ACH; i += 512)
      __builtin_amdgcn_global_load_lds(
          (const __attribute__((address_space(1))) void*)
            (Ag + (long)(i >> 2) * K + k0 + (((i & 3) ^ ((i >> 3) & 3)) << 3)),
          (__attribute__((address_space(3))) void*)(&As[buf][i * 8]), 16, 0, 0);
    #pragma unroll
    for (int i = tid; i < BCH; i += 512)
      __builtin_amdgcn_global_load_lds(
          (const __attribute__((address_space(1))) void*)
            (Bg + (long)(i >> 2) * K + k0 + (((i & 3) ^ ((i >> 3) & 3)) << 3)),
          (__attribute__((address_space(3))) void*)(&Bs[buf][i * 8]), 16, 0, 0);
  };
  auto compute = [&](int buf) {
    bf16x8 af[FM], bfr[FN];
    #pragma unroll
    for (int m = 0; m < FM; ++m)
      af[m] = *reinterpret_cast<const bf16x8*>(&As[buf][(wm + m * 16 + lr15) * BK + lks]);
    #pragma unroll
    for (int n = 0; n < FN; ++n)
      bfr[n] = *reinterpret_cast<const bf16x8*>(&Bs[buf][(wn + n * 16 + lr15) * BK + lks]);
    #pragma unroll
    for (int m = 0; m < FM; ++m)
      #pragma unroll
      for (int n = 0; n < FN; ++n)
        acc[m][n] = __builtin_amdgcn_mfma_f32_16x16x32_bf16(af[m], bfr[n], acc[m][n], 0, 0, 0);
  };

  stage(0, 0);
  asm volatile("s_waitcnt vmcnt(0)" ::: "memory");
  __builtin_amdgcn_s_barrier();
  int cur = 0;
  for (int k0 = BK; k0 < K; k0 += BK) {
    stage(cur ^ 1, k0);      // prefetch next tile while computing current
    compute(cur);
    asm volatile("s_waitcnt vmcnt(0)" ::: "memory");
    __builtin_amdgcn_s_barrier();
    cur ^= 1;
  }
  compute(cur);

  const int r0 = (lane >> 4) << 2;
  #pragma unroll
  for (int m = 0; m < FM; ++m)
    #pragma unroll
    for (int n = 0; n < FN; ++n) {
      const int col = bn + wn + n * 16 + lr15;
      const long rowb = bm + wm + m * 16 + r0;
      #pragma unroll
      for (int j = 0; j < 4; ++j) {
        const long off = (rowb + j) * N + col;
        float v = acc[m][n][j];
        if constexpr (EPI == ME_BIAS_F32) {
          Cf[off] = v + bias[col];
        } else if constexpr (EPI == ME_ACC_F32) {
          Cf[off] += v;
        } else if constexpr (EPI == ME_SILU_BF16) {
          Cb[off] = __float2bfloat16(v / (1.0f + expf(-v)));
        } else {
          float g = __bfloat162float(gate[off]);
          Cb[off] = __float2bfloat16(v * g);
        }
      }
    }
}

// ------------- fused SwiGLU: out = silu(A@Wg^T) * (A@Wu^T), bf16 ----------
// exact round-3 structure (2-buf, vmcnt(0)): measured 236us / 782 TF.
template <int BM, int BN, int WROWS, int WCOLS>
__global__ __launch_bounds__(256, 2) void k_swiglu(
    const __hip_bfloat16* __restrict__ Abf,
    const __hip_bfloat16* __restrict__ Wgb,
    const __hip_bfloat16* __restrict__ Wub,
    __hip_bfloat16* __restrict__ Cb,
    int M, int N, int K) {
  constexpr int BK = 32;
  constexpr int WTM = BM / WROWS, WTN = BN / WCOLS;
  constexpr int FM = WTM / 16, FN = WTN / 16;
  constexpr int ACH = BM * BK / 8, BCH = BN * BK / 8;
  __shared__ __align__(16) __bf16 As[2][BM * BK];
  __shared__ __align__(16) __bf16 Gs[2][BN * BK];
  __shared__ __align__(16) __bf16 Us[2][BN * BK];
  const int tid = threadIdx.x;
  const int sw = raster_sw(blockIdx.x, gridDim.x);
  const int ntm = M / BM;
  const int bm = (sw % ntm) * BM, bn = (sw / ntm) * BN;
  const int lane = tid & 63, wv = tid >> 6;
  const int wm = (wv / WCOLS) * WTM, wn = (wv % WCOLS) * WTN;
  const int lr15 = lane & 15;
  const int lks = (((lane >> 4) << 3)) ^ ((((lr15 >> 1) & 3)) << 3);
  f32x4 accg[FM][FN] = {}, accu[FM][FN] = {};
  const __bf16* Ag = reinterpret_cast<const __bf16*>(Abf) + (long)bm * K;
  const __bf16* Gg = reinterpret_cast<const __bf16*>(Wgb) + (long)bn * K;
  const __bf16* Ug = reinterpret_cast<const __bf16*>(Wub) + (long)bn * K;

  auto stage = [&](int buf, int k0) {
    #pragma unroll
    for (int i = tid; i < ACH; i += 256)
      __builtin_amdgcn_global_load_lds(
          (const __attribute__((address_space(1))) void*)
            (Ag + (long)(i >> 2) * K + k0 + (((i & 3) ^ ((i >> 3) & 3)) << 3)),
          (__attribute__((address_space(3))) void*)(&As[buf][i * 8]), 16, 0, 0);
    #pragma unroll
    for (int i = tid; i < BCH; i += 256)
      __builtin_amdgcn_global_load_lds(
          (const __attribute__((address_space(1))) void*)
            (Gg + (long)(i >> 2) * K + k0 + (((i & 3) ^ ((i >> 3) & 3)) << 3)),
          (__attribute__((address_space(3))) void*)(&Gs[buf][i * 8]), 16, 0, 0);
    #pragma unroll
    for (int i = tid; i < BCH; i += 256)
      __builtin_amdgcn_global_load_lds(
          (const __attribute__((address_space(1))) void*)
            (Ug + (long)(i >> 2) * K + k0 + (((i & 3) ^ ((i >> 3) & 3)) << 3)),
          (__attribute__((address_space(3))) void*)(&Us[buf][i * 8]), 16, 0, 0);
  };
  auto compute = [&](int buf) {
    bf16x8 af[FM], gf[FN], uf[FN];
    #pragma unroll
    for (int m = 0; m < FM; ++m)
      af[m] = *reinterpret_cast<const bf16x8*>(&As[buf][(wm + m * 16 + lr15) * BK + lks]);
    #pragma unroll
    for (int n = 0; n < FN; ++n) {
      gf[n] = *reinterpret_cast<const bf16x8*>(&Gs[buf][(wn + n * 16 + lr15) * BK + lks]);
      uf[n] = *reinterpret_cast<const bf16x8*>(&Us[buf][(wn + n * 16 + lr15) * BK + lks]);
    }
    #pragma unroll
    for (int m = 0; m < FM; ++m)
      #pragma unroll
      for (int n = 0; n < FN; ++n) {
        accg[m][n] = __builtin_amdgcn_mfma_f32_16x16x32_bf16(af[m], gf[n], accg[m][n], 0, 0, 0);
        accu[m][n] = __builtin_amdgcn_mfma_f32_16x16x32_bf16(af[m], uf[n], accu[m][n], 0, 0, 0);
      }
  };

  stage(0, 0);
  asm volatile("s_waitcnt vmcnt(0)" ::: "memory");
  __builtin_amdgcn_s_barrier();
  int cur = 0;
  for (int k0 = BK; k0 < K; k0 += BK) {
    stage(cur ^ 1, k0);
    compute(cur);
    asm volatile("s_waitcnt vmcnt(0)" ::: "memory");
    __builtin_amdgcn_s_barrier();
    cur ^= 1;
  }
  compute(cur);

  const int r0 = (lane >> 4) << 2;
  #pragma unroll
  for (int m = 0; m < FM; ++m)
    #pragma unroll
    for (int n = 0; n < FN; ++n) {
      const int col = bn + wn + n * 16 + lr15;
      const long rowb = bm + wm + m * 16 + r0;
      #pragma unroll
      for (int j = 0; j < 4; ++j) {
        float g = accg[m][n][j], u = accu[m][n][j];
        Cb[(rowb + j) * N + col] = __float2bfloat16((g / (1.0f + expf(-g))) * u);
      }
    }
}

// ---------------- fp32 GEMM (head only, tiny M) ----------------
enum { EPI_STORE = 0, EPI_GELU = 3 };

template <int EPI, bool HAS_BIAS>
__global__ __launch_bounds__(256) void k_gemm(const float* __restrict__ A,
                                              const float* __restrict__ W,
                                              const float* __restrict__ bias,
                                              float* __restrict__ C,
                                              int M, int N, int K) {
  constexpr int BM = 64, BN = 64, BK = 16;
  __shared__ float As[BK][BM + 4];
  __shared__ float Ws[BK][BN + 4];
  const int bm = blockIdx.y * BM, bn = blockIdx.x * BN;
  const int tid = threadIdx.x;
  const int lr = tid >> 2;
  const int lc = (tid & 3) << 2;
  const int ty = tid >> 4, tx = tid & 15;
  float acc[4][4] = {};
  const int arow = bm + lr;
  const bool aok = arow < M;
  const float* Ap = A + (long)arow * K + lc;
  const float* Wp = W + (long)(bn + lr) * K + lc;
  for (int k0 = 0; k0 < K; k0 += BK) {
    float4 av = aok ? *reinterpret_cast<const float4*>(Ap + k0) : make_float4(0.f, 0.f, 0.f, 0.f);
    float4 wv = *reinterpret_cast<const float4*>(Wp + k0);
    As[lc + 0][lr] = av.x; As[lc + 1][lr] = av.y; As[lc + 2][lr] = av.z; As[lc + 3][lr] = av.w;
    Ws[lc + 0][lr] = wv.x; Ws[lc + 1][lr] = wv.y; Ws[lc + 2][lr] = wv.z; Ws[lc + 3][lr] = wv.w;
    __syncthreads();
    #pragma unroll
    for (int k = 0; k < BK; ++k) {
      float4 a4 = *reinterpret_cast<const float4*>(&As[k][ty << 2]);
      float4 b4 = *reinterpret_cast<const float4*>(&Ws[k][tx << 2]);
      float a[4] = {a4.x, a4.y, a4.z, a4.w};
      float b[4] = {b4.x, b4.y, b4.z, b4.w};
      #pragma unroll
      for (int i = 0; i < 4; ++i)
        #pragma unroll
        for (int j = 0; j < 4; ++j) acc[i][j] = fmaf(a[i], b[j], acc[i][j]);
    }
    __syncthreads();
  }
  const int col = bn + (tx << 2);
  #pragma unroll
  for (int i = 0; i < 4; ++i) {
    int row = bm + (ty << 2) + i;
    if (row < M) {
      float4 r = make_float4(acc[i][0], acc[i][1], acc[i][2], acc[i][3]);
      if (HAS_BIAS) {
        float4 bv = *reinterpret_cast<const float4*>(bias + col);
        r.x += bv.x; r.y += bv.y; r.z += bv.z; r.w += bv.w;
      }
      if (EPI == EPI_GELU) {
        r.x = 0.5f * r.x * (1.0f + erff(r.x * 0.70710678118654752f));
        r.y = 0.5f * r.y * (1.0f + erff(r.y * 0.70710678118654752f));
        r.z = 0.5f * r.z * (1.0f + erff(r.z * 0.70710678118654752f));
        r.w = 0.5f * r.w * (1.0f + erff(r.w * 0.70710678118654752f));
      }
      *reinterpret_cast<float4*>(C + (long)row * N + col) = r;
    }
  }
}

// ---------------- lora down: tmp[T,16] = x[T,H] @ A[16,H]^T ----------------
__global__ __launch_bounds__(256) void k_lora_down(const float* __restrict__ x,
                                                   const float* __restrict__ A,
                                                   float* __restrict__ tmp) {
  int t = blockIdx.x, tid = threadIdx.x;
  int r = tid & 15, sl = tid >> 4;
  const float* xr = x + (long)t * H + sl * 128;
  const float* Ar = A + (long)r * H + sl * 128;
  float p = 0.f;
  #pragma unroll 8
  for (int kk = 0; kk < 128; kk += 4) {
    float4 xv = *reinterpret_cast<const float4*>(xr + kk);
    float4 av = *reinterpret_cast<const float4*>(Ar + kk);
    p = fmaf(xv.x, av.x, p); p = fmaf(xv.y, av.y, p);
    p = fmaf(xv.z, av.z, p); p = fmaf(xv.w, av.w, p);
  }
  __shared__ float red[16][17];
  red[sl][r] = p;
  __syncthreads();
  if (tid < 16) {
    float s = 0.f;
    #pragma unroll
    for (int i = 0; i < 16; ++i) s += red[i][tid];
    tmp[t * RR + tid] = s;
  }
}

// ------ lora up add (strided C): C[t*ldC + n] += 2 * tmp[t,:] @ Bm[n,:] ----
__global__ __launch_bounds__(256) void k_lora_add(const float* __restrict__ tmp,
                                                  const float* __restrict__ Bm,
                                                  float* __restrict__ C, int ldC, int N) {
  long idx = (long)blockIdx.x * 256 + threadIdx.x;
  if (idx >= (long)TT * N) return;
  int t = (int)(idx / N), n = (int)(idx % N);
  const float* tr = tmp + (long)t * RR;
  const float* br = Bm + (long)n * RR;
  float s = 0.f;
  #pragma unroll
  for (int r = 0; r < RR; ++r) s = fmaf(tr[r], br[r], s);
  C[(long)t * ldC + n] += LSCALE * s;
}

// ---------------- RoPE table: tab[pos*64+j] = (cos,sin)(pos*invfreq(j)) ----
__global__ __launch_bounds__(256) void k_rope_tab(float2* __restrict__ tab) {
  int idx = blockIdx.x * 256 + threadIdx.x;   // 4096 entries
  if (idx >= SS * 64) return;
  int pos = idx >> 6, j = idx & 63;
  float inv = 1.0f / powf(1.0e6f, (float)(2 * j) * (1.0f / HD));
  float ang = (float)pos * inv;
  tab[idx] = make_float2(cosf(ang), sinf(ang));
}

// ---------------- RoPE in place on fused qkv [T, QKVD] ---------------------
__global__ __launch_bounds__(256) void k_rope(float* __restrict__ qkv,
                                              const float2* __restrict__ tab) {
  int t = blockIdx.x;
  const float2* trow = tab + (t & (SS - 1)) * 64;
  float* row = qkv + (long)t * QKVD;
  for (int idx = threadIdx.x; idx < NH * 64 + NKV * 64; idx += 256) {
    float* base;
    int j;
    if (idx < NH * 64) {
      int head = idx >> 6; j = idx & 63;
      base = row + head * HD;
    } else {
      int i2 = idx - NH * 64;
      int head = i2 >> 6; j = i2 & 63;
      base = row + H + head * HD;
    }
    float2 cs2 = trow[j];
    float lo = base[j], hi = base[j + 64];
    base[j]      = lo * cs2.x - hi * cs2.y;
    base[j + 64] = hi * cs2.x + lo * cs2.y;
  }
}

// ---------------- fused attention: one wave per (b, head, query) -----------
__global__ __launch_bounds__(64) void k_attn(const float* __restrict__ qkv,
                                             const int* __restrict__ mask,
                                             float* __restrict__ o,
                                             __hip_bfloat16* __restrict__ obf) {
  int flat = blockIdx.x;
  int qi = flat & (SS - 1);
  int hh = (flat >> 6) & (NH - 1);
  int b  = flat >> 10;
  int lane = threadIdx.x;
  int kv = hh >> 3;  // NH/NKV = 8
  long t = (long)b * SS + qi;
  const float* qr = qkv + t * QKVD + hh * HD;
  const float* kr = qkv + ((long)b * SS + lane) * QKVD + H + kv * HD;
  float dot = 0.f;
  #pragma unroll 8
  for (int d = 0; d < HD; d += 4) {
    float4 qv = *reinterpret_cast<const float4*>(qr + d);
    float4 kvv = *reinterpret_cast<const float4*>(kr + d);
    dot = fmaf(qv.x, kvv.x, dot); dot = fmaf(qv.y, kvv.y, dot);
    dot = fmaf(qv.z, kvv.z, dot); dot = fmaf(qv.w, kvv.w, dot);
  }
  bool keep = (lane <= qi) && (mask[b * SS + lane] > 0);
  float sc = dot * 0.08838834764831845f + (keep ? 0.f : -1e9f);
  float m = sc;
  #pragma unroll
  for (int off = 32; off; off >>= 1) m = fmaxf(m, __shfl_xor(m, off));
  float e = expf(sc - m);
  float s = e;
  #pragma unroll
  for (int off = 32; off; off >>= 1) s += __shfl_xor(s, off);
  float p = e / s;
  __shared__ float pl[64];
  pl[lane] = p;
  __syncthreads();
  float o0 = 0.f, o1 = 0.f;
  const float* vb = qkv + (long)b * SS * QKVD + H + KVD + kv * HD;
  for (int ki = 0; ki < SS; ++ki) {
    float pp = pl[ki];
    o0 = fmaf(pp, vb[(long)ki * QKVD + lane], o0);
    o1 = fmaf(pp, vb[(long)ki * QKVD + lane + 64], o1);
  }
  long oidx = t * H + hh * HD + lane;
  o[oidx] = o0;
  o[oidx + 64] = o1;
  __hip_bfloat16 b0 = __float2bfloat16(o0), b1 = __float2bfloat16(o1);
  obf[oidx] = b0;
  obf[oidx + 64] = b1;
}

// ---------------- pool last valid token ----------------
__global__ __launch_bounds__(256) void k_pool(const float* __restrict__ x,
                                              const int* __restrict__ mask,
                                              float* __restrict__ pooled) {
  int b = blockIdx.x;
  __shared__ int len;
  if (threadIdx.x == 0) {
    int L2 = 0;
    for (int i = 0; i < SS; ++i) L2 += (mask[b * SS + i] > 0);
    len = L2;
  }
  __syncthreads();
  const float4* sp = reinterpret_cast<const float4*>(x + ((long)b * SS + len - 1) * H);
  float4* dp = reinterpret_cast<float4*>(pooled + (long)b * H);
  for (int i = threadIdx.x; i < H / 4; i += 256) dp[i] = sp[i];
}

// ---------------- launch helpers ----------------
static inline int cvt_grid(long n) { return (int)((n / 4 + 255) / 256); }

extern "C" void kernel_launch(void* const* d_in, const int* in_sizes, int n_in,
                              void* d_out, int out_size, void* d_ws, size_t ws_size,
                              hipStream_t stream) {
  const int*   ids    = (const int*)d_in[0];
  const int*   mask   = (const int*)d_in[1];
  const float* embed  = (const float*)d_in[2];
  const float* Wq     = (const float*)d_in[3];
  const float* bq     = (const float*)d_in[4];
  const float* Aq     = (const float*)d_in[5];
  const float* Bq     = (const float*)d_in[6];
  const float* Wk     = (const float*)d_in[7];
  const float* bk     = (const float*)d_in[8];
  const float* Ak     = (const float*)d_in[9];
  const float* Bk     = (const float*)d_in[10];
  const float* Wv     = (const float*)d_in[11];
  const float* bv     = (const float*)d_in[12];
  const float* Av     = (const float*)d_in[13];
  const float* Bv     = (const float*)d_in[14];
  const float* Wo     = (const float*)d_in[15];
  const float* Ao     = (const float*)d_in[16];
  const float* Bo     = (const float*)d_in[17];
  const float* ln1    = (const float*)d_in[18];
  const float* ln2    = (const float*)d_in[19];
  const float* Wg     = (const float*)d_in[20];
  const float* Wu     = (const float*)d_in[21];
  const float* Wd     = (const float*)d_in[22];
  const float* norm_f = (const float*)d_in[23];
  const float* W1     = (const float*)d_in[24];
  const float* b1     = (const float*)d_in[25];
  const float* W2     = (const float*)d_in[26];
  const float* b2     = (const float*)d_in[27];

  // ---- workspace layout ----
  float* ws = (float*)d_ws;
  float* h       = ws;                          // [T,H] fp32 residual
  float* x       = h    + (long)TT * H;         // [T,H] fp32 (normed / attn out)
  float* qkv     = x    + (long)TT * H;         // [T,QKVD] fp32
  float* tmpR    = qkv  + (long)TT * QKVD;      // [T,R]
  float* pooled  = tmpR + (long)TT * RR;        // [B,H]
  float* zz      = pooled + (long)BB * H;       // [B,PH]
  float* biascat = zz   + (long)BB * PH;        // [QKVD]
  float2* ropetab = (float2*)(biascat + QKVD);  // [SS*64]
  float* endf32  = (float*)(ropetab + SS * 64);
  __hip_bfloat16* x_bf = (__hip_bfloat16*)endf32;             // [T,H] bf16
  __hip_bfloat16* ffbf = x_bf + (long)TT * H;                 // [T,FF] bf16
  __hip_bfloat16* wbf  = ffbf + (long)TT * FF;                // [FF,H] bf16 weight scratch
  __hip_bfloat16* wbf2 = wbf  + (long)FF * H;                 // [FF,H] second weight scratch
  size_t need_fused = (size_t)((char*)(wbf2 + (long)FF * H) - (char*)d_ws);
  bool fused_ok = ws_size >= need_fused;

  k_embed<<<TT, 256, 0, stream>>>(ids, embed, h);
  k_rope_tab<<<(SS * 64 + 255) / 256, 256, 0, stream>>>(ropetab);

  for (int l = 0; l < NL; ++l) {
    const long lHH = (long)l * H * H;
    const long lKH = (long)l * KVD * H;
    const long lRH = (long)l * RR * H;
    // x,x_bf = rms(h, ln1)
    k_rmsnorm<<<TT, 256, 0, stream>>>(h, ln1 + l * H, x, x_bf);
    // fused QKV weight + bias
    k_cvt<<<cvt_grid((long)H * H), 256, 0, stream>>>(Wq + lHH, wbf, (long)H * H);
    k_cvt<<<cvt_grid((long)KVD * H), 256, 0, stream>>>(Wk + lKH, wbf + (long)H * H, (long)KVD * H);
    k_cvt<<<cvt_grid((long)KVD * H), 256, 0, stream>>>(Wv + lKH, wbf + (long)(H + KVD) * H, (long)KVD * H);
    hipMemcpyAsync(biascat,           bq + (long)l * H,   H * sizeof(float),   hipMemcpyDeviceToDevice, stream);
    hipMemcpyAsync(biascat + H,       bk + (long)l * KVD, KVD * sizeof(float), hipMemcpyDeviceToDevice, stream);
    hipMemcpyAsync(biascat + H + KVD, bv + (long)l * KVD, KVD * sizeof(float), hipMemcpyDeviceToDevice, stream);
    // qkv = x @ [Wq;Wk;Wv]^T + bias
    k_mgemm<ME_BIAS_F32><<<(TT / 128) * (QKVD / 128), 512, 0, stream>>>(
        x_bf, wbf, biascat, qkv, nullptr, nullptr, TT, QKVD, H);
    // lora adds for q/k/v
    k_lora_down<<<TT, 256, 0, stream>>>(x, Aq + lRH, tmpR);
    k_lora_add<<<((long)TT * H + 255) / 256, 256, 0, stream>>>(tmpR, Bq + (long)l * H * RR, qkv, QKVD, H);
    k_lora_down<<<TT, 256, 0, stream>>>(x, Ak + lRH, tmpR);
    k_lora_add<<<((long)TT * KVD + 255) / 256, 256, 0, stream>>>(tmpR, Bk + (long)l * KVD * RR, qkv + H, QKVD, KVD);
    k_lora_down<<<TT, 256, 0, stream>>>(x, Av + lRH, tmpR);
    k_lora_add<<<((long)TT * KVD + 255) / 256, 256, 0, stream>>>(tmpR, Bv + (long)l * KVD * RR, qkv + H + KVD, QKVD, KVD);
    // rope + attention (writes fp32 x and bf16 x_bf)
    k_rope<<<TT, 256, 0, stream>>>(qkv, ropetab);
    k_attn<<<BB * NH * SS, 64, 0, stream>>>(qkv, mask, x, x_bf);
    // h += attn @ Wo^T + lora
    k_lora_down<<<TT, 256, 0, stream>>>(x, Ao + lRH, tmpR);
    k_cvt<<<cvt_grid((long)H * H), 256, 0, stream>>>(Wo + lHH, wbf, (long)H * H);
    k_mgemm<ME_ACC_F32><<<(TT / 128) * (H / 128), 512, 0, stream>>>(
        x_bf, wbf, nullptr, h, nullptr, nullptr, TT, H, H);
    k_lora_add<<<((long)TT * H + 255) / 256, 256, 0, stream>>>(tmpR, Bo + (long)l * H * RR, h, H, H);
    // MLP
    k_rmsnorm<<<TT, 256, 0, stream>>>(h, ln2 + l * H, x, x_bf);
    if (fused_ok) {
      k_cvt<<<cvt_grid((long)FF * H), 256, 0, stream>>>(Wg + (long)l * FF * H, wbf, (long)FF * H);
      k_cvt<<<cvt_grid((long)FF * H), 256, 0, stream>>>(Wu + (long)l * FF * H, wbf2, (long)FF * H);
      k_swiglu<128, 128, 2, 2><<<(TT / 128) * (FF / 128), 256, 0, stream>>>(
          x_bf, wbf, wbf2, ffbf, TT, FF, H);
    } else {
      k_cvt<<<cvt_grid((long)FF * H), 256, 0, stream>>>(Wg + (long)l * FF * H, wbf, (long)FF * H);
      k_mgemm<ME_SILU_BF16><<<(TT / 128) * (FF / 128), 512, 0, stream>>>(
          x_bf, wbf, nullptr, nullptr, ffbf, nullptr, TT, FF, H);
      k_cvt<<<cvt_grid((long)FF * H), 256, 0, stream>>>(Wu + (long)l * FF * H, wbf, (long)FF * H);
      k_mgemm<ME_MUL_BF16><<<(TT / 128) * (FF / 128), 512, 0, stream>>>(
          x_bf, wbf, nullptr, nullptr, ffbf, ffbf, TT, FF, H);
    }
    k_cvt<<<cvt_grid((long)H * FF), 256, 0, stream>>>(Wd + (long)l * H * FF, wbf, (long)H * FF);
    k_mgemm<ME_ACC_F32><<<(TT / 128) * (H / 128), 512, 0, stream>>>(
        ffbf, wbf, nullptr, h, nullptr, nullptr, TT, H, FF);
  }

  // final norm, pool, head (fp32)
  k_rmsnorm<<<TT, 256, 0, stream>>>(h, norm_f, x, x_bf);
  k_pool<<<BB, 256, 0, stream>>>(x, mask, pooled);
  k_gemm<EPI_GELU, true><<<dim3(PH / 64, 1), 256, 0, stream>>>(pooled, W1, b1, zz, BB, PH, H);
  k_gemm<EPI_STORE, true><<<dim3(TDm / 64, 1), 256, 0, stream>>>(zz, W2, b2, (float*)d_out, BB, TDm, PH);
}